// Round 11
// baseline (467.011 us; speedup 1.0000x reference)
//
#include <hip/hip_runtime.h>
#include <hip/hip_bf16.h>
#include <hip/hip_cooperative_groups.h>
#include <math.h>

namespace cg = cooperative_groups;

#define NFLOWS 5
#define DIMF 64
#define HID 8192
#define BATCHN 4096

typedef unsigned int u32;
typedef __bf16 bf16x8 __attribute__((ext_vector_type(8)));
typedef float f32x4 __attribute__((ext_vector_type(4)));

__device__ __forceinline__ short f2bf_s(float x){
  u32 b = __float_as_uint(x);
  b += 0x7fff + ((b >> 16) & 1);          // RNE
  return (short)(b >> 16);
}
__device__ __forceinline__ u32 pk_bf16(float a, float b){
#if __has_builtin(__builtin_amdgcn_cvt_pk_bf16_f32)
  typedef __bf16 bf16x2_t __attribute__((ext_vector_type(2)));
  bf16x2_t r = __builtin_amdgcn_cvt_pk_bf16_f32(a, b);
  return __builtin_bit_cast(u32, r);
#else
  u32 x = __float_as_uint(a); x += 0x7fff + ((x >> 16) & 1);
  u32 y = __float_as_uint(b); y += 0x7fff + ((y >> 16) & 1);
  return (x >> 16) | (y & 0xffff0000u);
#endif
}
__device__ __forceinline__ float softplus_f(float z){
  return fmaxf(z, 0.f) + log1pf(__expf(-fabsf(z)));
}

// ================= single cooperative kernel: prep + 5 flows =================
// 256 blocks x 1024 threads, exactly co-resident (147 KB LDS -> 1 block/CU).
// Phase A: all 40960 W1 rows over all 4096 waves (10 rows/wave) -> wn1s + g1.
// Phase B: 320 (f,i) units on first 320 waves -> wn2s + expc4 + cmax.
// grid.sync() between phases provides device-scope visibility (G16).
// Main: r10 body verbatim (measured 187.9 us).
// wn1s layout: [f][i][nt(8)][ks2(2)][lane(64)][8]
// wn2s layout: [f][i][ks(4)][mt(4)][lane(64)][8]
__global__ __launch_bounds__(1024, 4)
void bnaf_coop_kernel(
    const float* __restrict__ x_in,
    const float* __restrict__ W1, const float* __restrict__ d1,
    const float* __restrict__ b1,
    const float* __restrict__ W2, const float* __restrict__ d2,
    const float* __restrict__ b2, const float* __restrict__ gates,
    short* __restrict__ wn1s, short* __restrict__ wn2s,
    float* __restrict__ expc4, float* __restrict__ cmax,
    float* __restrict__ g1, float* __restrict__ out)
{
  cg::grid_group grid = cg::this_grid();

  // LDS map (bytes) — main phase only:
  //   0      .. 4351    xs   fp32 x [16][68]
  //   4352   .. 6527    xb   bf16 B-frags of x (kb-stride 136 shorts)
  //   6528   .. 145791  t    per-wave DUAL bf16 t^T buffers (2 x 4352 B);
  //                          buf0 reused as y-partials [16][65] f32 at flow end
  //   145792 .. 146815  ldp  [16][16] f32
  __shared__ __attribute__((aligned(16))) char smem[146816];
  float* xs  = (float*)smem;
  short* xbS = (short*)(smem + 4352);
  float* ldp = (float*)(smem + 145792);

  const int tid  = threadIdx.x;
  const int w    = tid >> 6;      // wave 0..15
  const int lane = tid & 63;

  // ---------------- phase A: wn1s + g1 ----------------
  {
    const int gw = blockIdx.x * 16 + w;           // global wave 0..4095
    const int ks2 = lane >> 5, q4 = (lane & 31) >> 3, j = lane & 7;
    #pragma unroll
    for (int it = 0; it < 10; ++it) {
      int R = gw * 10 + it;                       // 0..40959
      int f = R >> 13, rl = R & (HID - 1);
      int i = rl >> 7, rr = rl & 127;
      float Wv = W1[(size_t)R * 64 + lane];
      float wv = (lane == i) ? __expf(Wv) : ((lane < i) ? Wv : 0.f);
      float sq = wv * wv;
      #pragma unroll
      for (int m = 1; m < 64; m <<= 1) sq += __shfl_xor(sq, m, 64);
      float d1v = d1[R];
      float sc = __expf(d1v) * rsqrtf(sq);
      int nt = rr >> 4, n16 = rr & 15;
      size_t dst = ((((size_t)(f * 64 + i) * 8 + nt) * 2 + ks2) << 9)
                 + ((q4 * 16 + n16) << 3) + j;
      wn1s[dst] = f2bf_s(wv * sc);
      if (lane == i) g1[R] = d1v + Wv - 0.5f * __logf(sq);
    }
  }
  grid.sync();

  // ---------------- phase B: wn2s + expc4 + cmax ----------------
  {
    const int gw = blockIdx.x * 16 + w;
    if (gw < 320) {
      const int f = gw >> 6, i = gw & 63;
      const float* Wrow = W2 + ((size_t)(f * DIMF + i)) * HID;
      const float d2v = d2[f * DIMF + i];
      // pass 1: masked sum of squares
      float part = 0.f;
      #pragma unroll
      for (int e = 0; e < 16; ++e) {
        int k0 = e * 512 + lane * 8;
        int kb = k0 >> 7;
        float4 a = *(const float4*)(Wrow + k0);
        float4 b = *(const float4*)(Wrow + k0 + 4);
        float wv[8] = {a.x, a.y, a.z, a.w, b.x, b.y, b.z, b.w};
        if (kb == i) {
          #pragma unroll
          for (int e2 = 0; e2 < 8; ++e2) wv[e2] = __expf(wv[e2]);
        } else if (kb > i) {
          #pragma unroll
          for (int e2 = 0; e2 < 8; ++e2) wv[e2] = 0.f;
        }
        #pragma unroll
        for (int e2 = 0; e2 < 8; ++e2) part = fmaf(wv[e2], wv[e2], part);
      }
      #pragma unroll
      for (int m = 1; m < 64; m <<= 1) part += __shfl_xor(part, m, 64);
      float ls = __logf(part);
      float sc2 = __expf(d2v) * rsqrtf(part);

      // pass 2: swizzled bf16 store + diagonal c values (kept in registers)
      const int mt2 = i >> 4, c16r = i & 15;
      float cv[8];
      float lm = -1e30f;
      #pragma unroll
      for (int e = 0; e < 16; ++e) {
        int k0 = e * 512 + lane * 8;
        int kb = k0 >> 7;
        float4 a = *(const float4*)(Wrow + k0);
        float4 b = *(const float4*)(Wrow + k0 + 4);
        float wv[8] = {a.x, a.y, a.z, a.w, b.x, b.y, b.z, b.w};
        if (kb == i) {
          float4 ga = *(const float4*)(g1 + f * HID + k0);
          float4 gb = *(const float4*)(g1 + f * HID + k0 + 4);
          float gg[8] = {ga.x, ga.y, ga.z, ga.w, gb.x, gb.y, gb.z, gb.w};
          #pragma unroll
          for (int e2 = 0; e2 < 8; ++e2) {
            cv[e2] = gg[e2] + d2v + wv[e2] - 0.5f * ls;
            lm = fmaxf(lm, cv[e2]);
            wv[e2] = __expf(wv[e2]);
          }
        } else if (kb > i) {
          #pragma unroll
          for (int e2 = 0; e2 < 8; ++e2) wv[e2] = 0.f;
        }
        int ks = (k0 >> 5) & 3, qq = (k0 >> 3) & 3;
        size_t dst = ((((size_t)(f * 64 + kb) * 4 + ks) * 4 + mt2) << 9)
                   + ((qq * 16 + c16r) << 3);
        uint4 pk4;
        pk4.x = pk_bf16(wv[0]*sc2, wv[1]*sc2); pk4.y = pk_bf16(wv[2]*sc2, wv[3]*sc2);
        pk4.z = pk_bf16(wv[4]*sc2, wv[5]*sc2); pk4.w = pk_bf16(wv[6]*sc2, wv[7]*sc2);
        *(uint4*)(wn2s + dst) = pk4;
      }
      #pragma unroll
      for (int m = 1; m < 64; m <<= 1) lm = fmaxf(lm, __shfl_xor(lm, m, 64));
      // diag lanes (kb==i hit at e=i>>2, lane-group i&3) write expc4
      if ((lane >> 4) == (i & 3)) {
        int base = f * HID + i * 128 + (lane & 15) * 8;
        float4 ea, eb;
        ea.x = 4.f*__expf(cv[0]-lm); ea.y = 4.f*__expf(cv[1]-lm);
        ea.z = 4.f*__expf(cv[2]-lm); ea.w = 4.f*__expf(cv[3]-lm);
        eb.x = 4.f*__expf(cv[4]-lm); eb.y = 4.f*__expf(cv[5]-lm);
        eb.z = 4.f*__expf(cv[6]-lm); eb.w = 4.f*__expf(cv[7]-lm);
        *(float4*)(expc4 + base)     = ea;
        *(float4*)(expc4 + base + 4) = eb;
      }
      if (lane == 0) cmax[f * DIMF + i] = lm;
    }
  }
  grid.sync();

  // ---------------- main: all 5 flows (r10 body) ----------------
  const int c16  = lane & 15;
  const int q    = lane >> 4;
  const int r0   = blockIdx.x * 16;

  short* tbuf0 = (short*)(smem + 6528 + w * 8704);
  short* tbuf1 = (short*)(smem + 6528 + w * 8704 + 4352);

  {
    int row = tid >> 6, col = tid & 63;
    float v = x_in[((size_t)(r0 + row) << 6) | col];
    xs[row * 68 + col] = v;
    xbS[(col >> 3) * 136 + row * 8 + (col & 7)] = f2bf_s(v);
  }
  float ldtot = 0.f;
  __syncthreads();

  #pragma unroll 1
  for (int f = 0; f < NFLOWS; ++f) {
    const float gatev = (f < NFLOWS - 1) ? gates[f] : 0.f;
    const float spg   = (f < NFLOWS - 1) ? softplus_f(gatev) : 0.f;

    // x B-frags for both k-steps (K=64), shared by all iters of this flow
    const bf16x8 xa0 = *(const bf16x8*)(xbS + q * 136 + c16 * 8);
    const bf16x8 xa1 = *(const bf16x8*)(xbS + (4 + q) * 136 + c16 * 8);

    f32x4 yacc[4];
    #pragma unroll
    for (int n = 0; n < 4; ++n) yacc[n] = f32x4{0.f, 0.f, 0.f, 0.f};
    float ldacc = 0.f;

    #pragma unroll 1
    for (int ii = 0; ii < 4; ++ii) {
      const int i = ii * 16 + w;                 // hidden block (dim index)
      short* tb = (ii & 1) ? tbuf1 : tbuf0;
      const short* p1l = wn1s + (((size_t)(f * 64 + i)) << 13) + lane * 8;
      const float* b1p = b1    + f * HID + i * 128 + q * 4;
      const float* ecp = expc4 + f * HID + i * 128 + q * 4;
      const bool hiHalf = (i >= 32);  // feats 32..63 all-zero for i < 32

      float s0 = 0.f, s1 = 0.f;
      f32x4 dd[4];

      // ================= half 0: nt 0..3 =================
      #pragma unroll
      for (int nt = 0; nt < 4; ++nt) {
        float4 b1q = *(const float4*)(b1p + nt * 16);
        f32x4 z = {b1q.x, b1q.y, b1q.z, b1q.w};
        bf16x8 bw0 = *(const bf16x8*)(p1l + nt * 1024);
        dd[nt] = __builtin_amdgcn_mfma_f32_16x16x32_bf16(bw0, xa0, z, 0, 0, 0);
      }
      if (hiHalf) {
        #pragma unroll
        for (int nt = 0; nt < 4; ++nt) {
          bf16x8 bw1 = *(const bf16x8*)(p1l + nt * 1024 + 512);
          dd[nt] = __builtin_amdgcn_mfma_f32_16x16x32_bf16(bw1, xa1, dd[nt], 0, 0, 0);
        }
      }
      #pragma unroll
      for (int nt = 0; nt < 4; ++nt) {
        float4 ecq = *(const float4*)(ecp + nt * 16);
        float t[4];
        #pragma unroll
        for (int r = 0; r < 4; ++r) {
          float ee = (r == 0) ? ecq.x : (r == 1) ? ecq.y : (r == 2) ? ecq.z : ecq.w;
          float h  = dd[nt][r];
          float up = __expf(-2.f * fabsf(h));              // e^{-2|h|}
          float vp = __builtin_amdgcn_rcpf(1.f + up);
          float ta = fmaf(-2.f * up, vp, 1.f);             // tanh(|h|)
          t[r] = copysignf(ta, h);
          float c1 = ee * up, c2 = vp * vp;
          if (r & 1) s1 = fmaf(c1, c2, s1); else s0 = fmaf(c1, c2, s0);
        }
        uint2 pk; pk.x = pk_bf16(t[0], t[1]); pk.y = pk_bf16(t[2], t[3]);
        *(uint2*)(tb + c16 * 136 + nt * 16 + q * 4) = pk;
      }

      // ---- deferred GEMM2' for hidden block ii-1 (dd dead here) ----
      if (ii > 0) {
        const int ip = i - 16;
        short* tp = ((ii - 1) & 1) ? tbuf1 : tbuf0;
        __builtin_amdgcn_sched_barrier(0);
        asm volatile("s_waitcnt lgkmcnt(0)" ::: "memory");
        const short* p2l = wn2s + (((size_t)(f * 64 + ip)) << 13) + lane * 8;
        const int mt0 = ip >> 4;
        #pragma unroll
        for (int ks = 0; ks < 4; ++ks) {
          if (ks == 2) __builtin_amdgcn_sched_barrier(0);
          bf16x8 tfrag = *(const bf16x8*)(tp + c16 * 136 + ks * 32 + q * 8);
          #pragma unroll
          for (int mt = 0; mt < 4; ++mt) {
            if (mt >= mt0) {
              bf16x8 wb = *(const bf16x8*)(p2l + (ks * 4 + mt) * 512);
              yacc[mt] = __builtin_amdgcn_mfma_f32_16x16x32_bf16(wb, tfrag, yacc[mt], 0, 0, 0);
            }
          }
        }
        __builtin_amdgcn_sched_barrier(0);
      }

      // ================= half 1: nt 4..7 (reuse dd) =================
      #pragma unroll
      for (int nt = 0; nt < 4; ++nt) {
        float4 b1q = *(const float4*)(b1p + (nt + 4) * 16);
        f32x4 z = {b1q.x, b1q.y, b1q.z, b1q.w};
        bf16x8 bw0 = *(const bf16x8*)(p1l + (nt + 4) * 1024);
        dd[nt] = __builtin_amdgcn_mfma_f32_16x16x32_bf16(bw0, xa0, z, 0, 0, 0);
      }
      if (hiHalf) {
        #pragma unroll
        for (int nt = 0; nt < 4; ++nt) {
          bf16x8 bw1 = *(const bf16x8*)(p1l + (nt + 4) * 1024 + 512);
          dd[nt] = __builtin_amdgcn_mfma_f32_16x16x32_bf16(bw1, xa1, dd[nt], 0, 0, 0);
        }
      }
      #pragma unroll
      for (int nt = 0; nt < 4; ++nt) {
        float4 ecq = *(const float4*)(ecp + (nt + 4) * 16);
        float t[4];
        #pragma unroll
        for (int r = 0; r < 4; ++r) {
          float ee = (r == 0) ? ecq.x : (r == 1) ? ecq.y : (r == 2) ? ecq.z : ecq.w;
          float h  = dd[nt][r];
          float up = __expf(-2.f * fabsf(h));
          float vp = __builtin_amdgcn_rcpf(1.f + up);
          float ta = fmaf(-2.f * up, vp, 1.f);
          t[r] = copysignf(ta, h);
          float c1 = ee * up, c2 = vp * vp;
          if (r & 1) s1 = fmaf(c1, c2, s1); else s0 = fmaf(c1, c2, s0);
        }
        uint2 pk; pk.x = pk_bf16(t[0], t[1]); pk.y = pk_bf16(t[2], t[3]);
        *(uint2*)(tb + c16 * 136 + (nt + 4) * 16 + q * 4) = pk;
      }

      // ---- lse reduce over q-lanes; grad for this (batch row c16, dim i) ----
      float sacc = s0 + s1;
      sacc += __shfl_xor(sacc, 16, 64);
      sacc += __shfl_xor(sacc, 32, 64);
      const float Mi = cmax[f * DIMF + i];
      float grad = Mi + __logf(sacc);
      ldacc += (f < NFLOWS - 1) ? (softplus_f(grad + gatev) - spg) : grad;
    } // hidden blocks

    // ---- final deferred GEMM2 (ii = 3, buffer 1) ----
    {
      const int ip = 48 + w;
      __builtin_amdgcn_sched_barrier(0);
      asm volatile("s_waitcnt lgkmcnt(0)" ::: "memory");
      const short* p2l = wn2s + (((size_t)(f * 64 + ip)) << 13) + lane * 8;
      const int mt0 = ip >> 4;
      #pragma unroll
      for (int ks = 0; ks < 4; ++ks) {
        if (ks == 2) __builtin_amdgcn_sched_barrier(0);
        bf16x8 tfrag = *(const bf16x8*)(tbuf1 + c16 * 136 + ks * 32 + q * 8);
        #pragma unroll
        for (int mt = 0; mt < 4; ++mt) {
          if (mt >= mt0) {
            bf16x8 wb = *(const bf16x8*)(p2l + (ks * 4 + mt) * 512);
            yacc[mt] = __builtin_amdgcn_mfma_f32_16x16x32_bf16(wb, tfrag, yacc[mt], 0, 0, 0);
          }
        }
      }
      __builtin_amdgcn_sched_barrier(0);
    }

    // ---- stage per-wave partials: stride-65 (conflict-free epilogue) ----
    float* ypw = (float*)(smem + 6528 + w * 8704);
    #pragma unroll
    for (int mt = 0; mt < 4; ++mt)
      #pragma unroll
      for (int r = 0; r < 4; ++r)
        ypw[(mt * 4 + r) * 65 + lane] = yacc[mt][r];
    if (q == 0) ldp[w * 16 + c16] = ldacc;
    __syncthreads();

    // ---- epilogue: reduce 16 waves, bias, gate, flip ----
    float sgate = 0.f;
    if (f < NFLOWS - 1) sgate = __builtin_amdgcn_rcpf(1.f + __expf(-gatev));
    int row = tid >> 6, col = tid & 63;
    int idx = ((col >> 4) * 4 + (col & 3)) * 65 + (((col >> 2) & 3) * 16 + row);
    float v = b2[f * DIMF + col];
    #pragma unroll
    for (int ww = 0; ww < 16; ++ww)
      v += ((const float*)(smem + 6528 + ww * 8704))[idx];
    float nx = 0.f; int nrow = 0, ncol = 0;
    if (f < NFLOWS - 1) {
      float xv = xs[row * 68 + col];
      nx = fmaf(sgate, v - xv, xv);        // s*y + (1-s)*x
      nrow = row; ncol = 63 - col;         // flip for next flow
    } else {
      out[((size_t)(r0 + row) << 6) | col] = v;
    }
    if (tid < 16) {
      float a = 0.f;
      #pragma unroll
      for (int ww = 0; ww < 16; ++ww) a += ldp[ww * 16 + tid];
      ldtot += a;
    }
    __syncthreads();
    if (f < NFLOWS - 1) {
      xs[nrow * 68 + ncol] = nx;
      xbS[(ncol >> 3) * 136 + nrow * 8 + (ncol & 7)] = f2bf_s(nx);
      __syncthreads();
    }
  } // flows

  if (tid < 16) out[(size_t)BATCHN * DIMF + r0 + tid] = ldtot;
}

extern "C" void kernel_launch(void* const* d_in, const int* in_sizes, int n_in,
                              void* d_out, int out_size, void* d_ws, size_t ws_size,
                              hipStream_t stream)
{
  const float* x     = (const float*)d_in[0];
  const float* W1    = (const float*)d_in[1];
  const float* d1    = (const float*)d_in[2];
  const float* b1    = (const float*)d_in[3];
  const float* W2    = (const float*)d_in[4];
  const float* d2    = (const float*)d_in[5];
  const float* b2    = (const float*)d_in[6];
  const float* gates = (const float*)d_in[7];
  float* out = (float*)d_out;

  char* ws = (char*)d_ws;
  short* wn1s  = (short*)ws;                                  // 5,242,880 B
  short* wn2s  = (short*)(ws + 5242880);                      // 5,242,880 B
  float* expc4 = (float*)(ws + 10485760);                     //   163,840 B
  float* cmaxp = (float*)(ws + 10649600);                     //     1,280 B
  float* g1    = (float*)(ws + 10650880);                     //   163,840 B

  void* args[] = {
    (void*)&x, (void*)&W1, (void*)&d1, (void*)&b1,
    (void*)&W2, (void*)&d2, (void*)&b2, (void*)&gates,
    (void*)&wn1s, (void*)&wn2s, (void*)&expc4, (void*)&cmaxp,
    (void*)&g1, (void*)&out
  };
  hipLaunchCooperativeKernel((const void*)bnaf_coop_kernel,
                             dim3(256), dim3(1024), args, 0, stream);
}

// Round 12
// 262.936 us; speedup vs baseline: 1.7761x; 1.7761x over previous
//
#include <hip/hip_runtime.h>
#include <hip/hip_bf16.h>
#include <math.h>

#define NFLOWS 5
#define DIMF 64
#define HID 8192
#define BATCHN 4096

typedef unsigned int u32;
typedef __bf16 bf16x8 __attribute__((ext_vector_type(8)));
typedef float f32x4 __attribute__((ext_vector_type(4)));

__device__ __forceinline__ short f2bf_s(float x){
  u32 b = __float_as_uint(x);
  b += 0x7fff + ((b >> 16) & 1);          // RNE
  return (short)(b >> 16);
}
__device__ __forceinline__ u32 pk_bf16(float a, float b){
#if __has_builtin(__builtin_amdgcn_cvt_pk_bf16_f32)
  typedef __bf16 bf16x2_t __attribute__((ext_vector_type(2)));
  bf16x2_t r = __builtin_amdgcn_cvt_pk_bf16_f32(a, b);
  return __builtin_bit_cast(u32, r);
#else
  u32 x = __float_as_uint(a); x += 0x7fff + ((x >> 16) & 1);
  u32 y = __float_as_uint(b); y += 0x7fff + ((y >> 16) & 1);
  return (x >> 16) | (y & 0xffff0000u);
#endif
}
__device__ __forceinline__ float softplus_f(float z){
  return fmaxf(z, 0.f) + log1pf(__expf(-fabsf(z)));
}

// ---------------- fused prep: one block (1024 thr) per (flow f, block i) ----
// A0: per-row scale + g1 via shfl (no global stores)
// A1: fragment stores fully coalesced (one uint4 per thread, 1KB/64 lanes)
// B : W2 row (f,i) -> wn2s frags + cmax + expc4 (r10 verbatim)
// wn1s layout: [f][i][nt(8)][ks2(2)][lane(64)][8]
// wn2s layout: [f][i][ks(4)][mt(4)][lane(64)][8]
__global__ __launch_bounds__(1024) void prep_fused_kernel(
    const float* __restrict__ W1, const float* __restrict__ d1,
    const float* __restrict__ W2, const float* __restrict__ d2,
    short* __restrict__ wn1s, short* __restrict__ wn2s,
    float* __restrict__ expc4, float* __restrict__ cmax)
{
  __shared__ float scl[128];
  __shared__ float g1s[128];
  __shared__ float cbuf[128];
  __shared__ float red[16];
  __shared__ float Msh;

  const int tid  = threadIdx.x;
  const int w    = tid >> 6;      // 0..15
  const int lane = tid & 63;
  const int f    = blockIdx.x >> 6;
  const int i    = blockIdx.x & 63;

  // ---------------- A0: row scales + g1 ----------------
  #pragma unroll
  for (int it = 0; it < 8; ++it) {
    int rr = w * 8 + it;                        // row within block (0..127)
    size_t R = (size_t)(f * HID + i * 128 + rr);
    float Wv = W1[R * 64 + lane];
    float wv = (lane == i) ? __expf(Wv) : ((lane < i) ? Wv : 0.f);
    float sq = wv * wv;
    #pragma unroll
    for (int m = 1; m < 64; m <<= 1) sq += __shfl_xor(sq, m, 64);
    float d1v = d1[R];
    if (lane == 0) scl[rr] = __expf(d1v) * rsqrtf(sq);
    if (lane == i) g1s[rr] = d1v + Wv - 0.5f * __logf(sq);
  }
  __syncthreads();

  // ---------------- A1: coalesced fragment stores ----------------
  {
    const int c   = tid >> 6;          // chunk 0..15
    const int nt  = c >> 1, ks2 = c & 1;
    const int n16 = lane & 15, q4 = lane >> 4;
    const int row = nt * 16 + n16;
    const int k0  = ks2 * 32 + q4 * 8;
    const float* src = W1 + ((size_t)(f * HID + i * 128 + row)) * 64 + k0;
    float4 a = *(const float4*)src;
    float4 b = *(const float4*)(src + 4);
    float wv[8] = {a.x, a.y, a.z, a.w, b.x, b.y, b.z, b.w};
    float sc = scl[row];
    #pragma unroll
    for (int e = 0; e < 8; ++e) {
      int k = k0 + e;
      float v = (k == i) ? __expf(wv[e]) : ((k < i) ? wv[e] : 0.f);
      wv[e] = v * sc;
    }
    uint4 pk4;
    pk4.x = pk_bf16(wv[0], wv[1]); pk4.y = pk_bf16(wv[2], wv[3]);
    pk4.z = pk_bf16(wv[4], wv[5]); pk4.w = pk_bf16(wv[6], wv[7]);
    short* dstp = wn1s + ((((size_t)(f * 64 + i) * 8 + nt) * 2 + ks2) << 9)
                + lane * 8;
    *(uint4*)dstp = pk4;
  }

  // ---------------- phase B ----------------
  const float* Wrow = W2 + ((size_t)(f * DIMF + i)) * HID;
  const float d2v = d2[f * DIMF + i];
  const int k0 = tid * 8;
  const int kb = tid >> 4;
  float4 a = *(const float4*)(Wrow + k0);
  float4 b = *(const float4*)(Wrow + k0 + 4);
  float wv[8] = {a.x, a.y, a.z, a.w, b.x, b.y, b.z, b.w};
  const bool diag = (kb == i);
  float cv[8];
  float mv[8];
  #pragma unroll
  for (int e = 0; e < 8; ++e) {
    if (diag)        { cv[e] = g1s[(k0 - i * 128) + e] + d2v + wv[e]; mv[e] = __expf(wv[e]); }
    else if (kb > i) { mv[e] = 0.f; }
    else             { mv[e] = wv[e]; }
  }
  float part = 0.f;
  #pragma unroll
  for (int e = 0; e < 8; ++e) part = fmaf(mv[e], mv[e], part);
  #pragma unroll
  for (int m = 1; m < 64; m <<= 1) part += __shfl_xor(part, m, 64);
  if (lane == 0) red[w] = part;
  __syncthreads();
  float wsn = 0.f;
  #pragma unroll
  for (int e = 0; e < 16; ++e) wsn += red[e];
  float ls = __logf(wsn);
  float sc2 = __expf(d2v) * rsqrtf(wsn);

  if (diag) {
    int rr0 = k0 - i * 128;
    #pragma unroll
    for (int e = 0; e < 8; ++e) cbuf[rr0 + e] = cv[e] - 0.5f * ls;
  }
  {
    int ks = (k0 >> 5) & 3, qq = (k0 >> 3) & 3;
    int mt2 = i >> 4, c16r = i & 15;
    size_t dst = ((((size_t)(f * 64 + kb) * 4 + ks) * 4 + mt2) << 9)
               + ((qq * 16 + c16r) << 3);
    uint4 pk4;
    pk4.x = pk_bf16(mv[0]*sc2, mv[1]*sc2); pk4.y = pk_bf16(mv[2]*sc2, mv[3]*sc2);
    pk4.z = pk_bf16(mv[4]*sc2, mv[5]*sc2); pk4.w = pk_bf16(mv[6]*sc2, mv[7]*sc2);
    *(uint4*)(wn2s + dst) = pk4;
  }
  __syncthreads();

  if (w == 0) {
    float m = fmaxf(cbuf[lane], cbuf[lane + 64]);
    #pragma unroll
    for (int s = 1; s < 64; s <<= 1) m = fmaxf(m, __shfl_xor(m, s, 64));
    if (lane == 0) { cmax[f * DIMF + i] = m; Msh = m; }
  }
  __syncthreads();
  if (tid < 128) expc4[f * HID + i * 128 + tid] = 4.f * __expf(cbuf[tid] - Msh);
}

// ---------------- main fused kernel: all 5 flows, pipelined MFMA -----
// 256 blocks x 1024 threads (16 waves). Block owns 16 batch rows; each wave
// owns 4 of the 64 hidden blocks. x persists in LDS across flows.
// r10 body verbatim — measured 187.9 us, converged across 3 orderings.
__global__ __launch_bounds__(1024, 4)
void bnaf_main_kernel(
    const float* __restrict__ x_in,
    const float* __restrict__ b1, const float* __restrict__ b2,
    const float* __restrict__ gates,
    const short* __restrict__ wn1s,
    const short* __restrict__ wn2s,
    const float* __restrict__ expc4, const float* __restrict__ cmax,
    float* __restrict__ out)
{
  // LDS map (bytes):
  //   0      .. 4351    xs   fp32 x [16][68]
  //   4352   .. 6527    xb   bf16 B-frags of x (kb-stride 136 shorts)
  //   6528   .. 145791  t    per-wave DUAL bf16 t^T buffers (2 x 4352 B);
  //                          buf0 reused as y-partials [16][65] f32 at flow end
  //   145792 .. 146815  ldp  [16][16] f32
  __shared__ __attribute__((aligned(16))) char smem[146816];
  float* xs  = (float*)smem;
  short* xbS = (short*)(smem + 4352);
  float* ldp = (float*)(smem + 145792);

  const int tid  = threadIdx.x;
  const int w    = tid >> 6;      // wave 0..15
  const int lane = tid & 63;
  const int c16  = lane & 15;
  const int q    = lane >> 4;
  const int r0   = blockIdx.x * 16;

  short* tbuf0 = (short*)(smem + 6528 + w * 8704);
  short* tbuf1 = (short*)(smem + 6528 + w * 8704 + 4352);

  {
    int row = tid >> 6, col = tid & 63;
    float v = x_in[((size_t)(r0 + row) << 6) | col];
    xs[row * 68 + col] = v;
    xbS[(col >> 3) * 136 + row * 8 + (col & 7)] = f2bf_s(v);
  }
  float ldtot = 0.f;
  __syncthreads();

  #pragma unroll 1
  for (int f = 0; f < NFLOWS; ++f) {
    const float gatev = (f < NFLOWS - 1) ? gates[f] : 0.f;
    const float spg   = (f < NFLOWS - 1) ? softplus_f(gatev) : 0.f;

    // x B-frags for both k-steps (K=64), shared by all iters of this flow
    const bf16x8 xa0 = *(const bf16x8*)(xbS + q * 136 + c16 * 8);
    const bf16x8 xa1 = *(const bf16x8*)(xbS + (4 + q) * 136 + c16 * 8);

    f32x4 yacc[4];
    #pragma unroll
    for (int n = 0; n < 4; ++n) yacc[n] = f32x4{0.f, 0.f, 0.f, 0.f};
    float ldacc = 0.f;

    #pragma unroll 1
    for (int ii = 0; ii < 4; ++ii) {
      const int i = ii * 16 + w;                 // hidden block (dim index)
      short* tb = (ii & 1) ? tbuf1 : tbuf0;
      const short* p1l = wn1s + (((size_t)(f * 64 + i)) << 13) + lane * 8;
      const float* b1p = b1    + f * HID + i * 128 + q * 4;
      const float* ecp = expc4 + f * HID + i * 128 + q * 4;
      const bool hiHalf = (i >= 32);  // feats 32..63 all-zero for i < 32

      float s0 = 0.f, s1 = 0.f;
      f32x4 dd[4];

      // ================= half 0: nt 0..3 =================
      #pragma unroll
      for (int nt = 0; nt < 4; ++nt) {
        float4 b1q = *(const float4*)(b1p + nt * 16);
        f32x4 z = {b1q.x, b1q.y, b1q.z, b1q.w};
        bf16x8 bw0 = *(const bf16x8*)(p1l + nt * 1024);
        dd[nt] = __builtin_amdgcn_mfma_f32_16x16x32_bf16(bw0, xa0, z, 0, 0, 0);
      }
      if (hiHalf) {
        #pragma unroll
        for (int nt = 0; nt < 4; ++nt) {
          bf16x8 bw1 = *(const bf16x8*)(p1l + nt * 1024 + 512);
          dd[nt] = __builtin_amdgcn_mfma_f32_16x16x32_bf16(bw1, xa1, dd[nt], 0, 0, 0);
        }
      }
      #pragma unroll
      for (int nt = 0; nt < 4; ++nt) {
        float4 ecq = *(const float4*)(ecp + nt * 16);
        float t[4];
        #pragma unroll
        for (int r = 0; r < 4; ++r) {
          float ee = (r == 0) ? ecq.x : (r == 1) ? ecq.y : (r == 2) ? ecq.z : ecq.w;
          float h  = dd[nt][r];
          float up = __expf(-2.f * fabsf(h));              // e^{-2|h|}
          float vp = __builtin_amdgcn_rcpf(1.f + up);
          float ta = fmaf(-2.f * up, vp, 1.f);             // tanh(|h|)
          t[r] = copysignf(ta, h);
          float c1 = ee * up, c2 = vp * vp;
          if (r & 1) s1 = fmaf(c1, c2, s1); else s0 = fmaf(c1, c2, s0);
        }
        uint2 pk; pk.x = pk_bf16(t[0], t[1]); pk.y = pk_bf16(t[2], t[3]);
        *(uint2*)(tb + c16 * 136 + nt * 16 + q * 4) = pk;
      }

      // ---- deferred GEMM2' for hidden block ii-1 (dd dead here) ----
      if (ii > 0) {
        const int ip = i - 16;
        short* tp = ((ii - 1) & 1) ? tbuf1 : tbuf0;
        __builtin_amdgcn_sched_barrier(0);   // fence: nothing crosses in
        asm volatile("s_waitcnt lgkmcnt(0)" ::: "memory");
        const short* p2l = wn2s + (((size_t)(f * 64 + ip)) << 13) + lane * 8;
        const int mt0 = ip >> 4;
        #pragma unroll
        for (int ks = 0; ks < 4; ++ks) {
          if (ks == 2) __builtin_amdgcn_sched_barrier(0);  // cap hoisted wb at 8
          bf16x8 tfrag = *(const bf16x8*)(tp + c16 * 136 + ks * 32 + q * 8);
          #pragma unroll
          for (int mt = 0; mt < 4; ++mt) {
            if (mt >= mt0) {
              bf16x8 wb = *(const bf16x8*)(p2l + (ks * 4 + mt) * 512);
              yacc[mt] = __builtin_amdgcn_mfma_f32_16x16x32_bf16(wb, tfrag, yacc[mt], 0, 0, 0);
            }
          }
        }
        __builtin_amdgcn_sched_barrier(0);   // fence: nothing crosses out
      }

      // ================= half 1: nt 4..7 (reuse dd) =================
      #pragma unroll
      for (int nt = 0; nt < 4; ++nt) {
        float4 b1q = *(const float4*)(b1p + (nt + 4) * 16);
        f32x4 z = {b1q.x, b1q.y, b1q.z, b1q.w};
        bf16x8 bw0 = *(const bf16x8*)(p1l + (nt + 4) * 1024);
        dd[nt] = __builtin_amdgcn_mfma_f32_16x16x32_bf16(bw0, xa0, z, 0, 0, 0);
      }
      if (hiHalf) {
        #pragma unroll
        for (int nt = 0; nt < 4; ++nt) {
          bf16x8 bw1 = *(const bf16x8*)(p1l + (nt + 4) * 1024 + 512);
          dd[nt] = __builtin_amdgcn_mfma_f32_16x16x32_bf16(bw1, xa1, dd[nt], 0, 0, 0);
        }
      }
      #pragma unroll
      for (int nt = 0; nt < 4; ++nt) {
        float4 ecq = *(const float4*)(ecp + (nt + 4) * 16);
        float t[4];
        #pragma unroll
        for (int r = 0; r < 4; ++r) {
          float ee = (r == 0) ? ecq.x : (r == 1) ? ecq.y : (r == 2) ? ecq.z : ecq.w;
          float h  = dd[nt][r];
          float up = __expf(-2.f * fabsf(h));
          float vp = __builtin_amdgcn_rcpf(1.f + up);
          float ta = fmaf(-2.f * up, vp, 1.f);
          t[r] = copysignf(ta, h);
          float c1 = ee * up, c2 = vp * vp;
          if (r & 1) s1 = fmaf(c1, c2, s1); else s0 = fmaf(c1, c2, s0);
        }
        uint2 pk; pk.x = pk_bf16(t[0], t[1]); pk.y = pk_bf16(t[2], t[3]);
        *(uint2*)(tb + c16 * 136 + (nt + 4) * 16 + q * 4) = pk;
      }

      // ---- lse reduce over q-lanes; grad for this (batch row c16, dim i) ----
      float sacc = s0 + s1;
      sacc += __shfl_xor(sacc, 16, 64);
      sacc += __shfl_xor(sacc, 32, 64);
      const float Mi = cmax[f * DIMF + i];
      float grad = Mi + __logf(sacc);
      ldacc += (f < NFLOWS - 1) ? (softplus_f(grad + gatev) - spg) : grad;
    } // hidden blocks

    // ---- final deferred GEMM2 (ii = 3, buffer 1) ----
    {
      const int ip = 48 + w;
      __builtin_amdgcn_sched_barrier(0);
      asm volatile("s_waitcnt lgkmcnt(0)" ::: "memory");
      const short* p2l = wn2s + (((size_t)(f * 64 + ip)) << 13) + lane * 8;
      const int mt0 = ip >> 4;
      #pragma unroll
      for (int ks = 0; ks < 4; ++ks) {
        if (ks == 2) __builtin_amdgcn_sched_barrier(0);
        bf16x8 tfrag = *(const bf16x8*)(tbuf1 + c16 * 136 + ks * 32 + q * 8);
        #pragma unroll
        for (int mt = 0; mt < 4; ++mt) {
          if (mt >= mt0) {
            bf16x8 wb = *(const bf16x8*)(p2l + (ks * 4 + mt) * 512);
            yacc[mt] = __builtin_amdgcn_mfma_f32_16x16x32_bf16(wb, tfrag, yacc[mt], 0, 0, 0);
          }
        }
      }
      __builtin_amdgcn_sched_barrier(0);
    }

    // ---- stage per-wave partials: stride-65 (conflict-free epilogue) ----
    float* ypw = (float*)(smem + 6528 + w * 8704);
    #pragma unroll
    for (int mt = 0; mt < 4; ++mt)
      #pragma unroll
      for (int r = 0; r < 4; ++r)
        ypw[(mt * 4 + r) * 65 + lane] = yacc[mt][r];
    if (q == 0) ldp[w * 16 + c16] = ldacc;
    __syncthreads();

    // ---- epilogue: reduce 16 waves, bias, gate, flip ----
    float sgate = 0.f;
    if (f < NFLOWS - 1) sgate = __builtin_amdgcn_rcpf(1.f + __expf(-gatev));
    int row = tid >> 6, col = tid & 63;
    // y value for (out col, batch row): reg = (col>>4)*4 + (col&3),
    // src lane = ((col>>2)&3)*16 + row; bank = reg + 16q + row (all 32, 2-way)
    int idx = ((col >> 4) * 4 + (col & 3)) * 65 + (((col >> 2) & 3) * 16 + row);
    float v = b2[f * DIMF + col];
    #pragma unroll
    for (int ww = 0; ww < 16; ++ww)
      v += ((const float*)(smem + 6528 + ww * 8704))[idx];
    float nx = 0.f; int nrow = 0, ncol = 0;
    if (f < NFLOWS - 1) {
      float xv = xs[row * 68 + col];
      nx = fmaf(sgate, v - xv, xv);        // s*y + (1-s)*x
      nrow = row; ncol = 63 - col;         // flip for next flow
    } else {
      out[((size_t)(r0 + row) << 6) | col] = v;
    }
    if (tid < 16) {
      float a = 0.f;
      #pragma unroll
      for (int ww = 0; ww < 16; ++ww) a += ldp[ww * 16 + tid];
      ldtot += a;
    }
    __syncthreads();
    if (f < NFLOWS - 1) {
      xs[nrow * 68 + ncol] = nx;
      xbS[(ncol >> 3) * 136 + nrow * 8 + (ncol & 7)] = f2bf_s(nx);
      __syncthreads();
    }
  } // flows

  if (tid < 16) out[(size_t)BATCHN * DIMF + r0 + tid] = ldtot;
}

extern "C" void kernel_launch(void* const* d_in, const int* in_sizes, int n_in,
                              void* d_out, int out_size, void* d_ws, size_t ws_size,
                              hipStream_t stream)
{
  const float* x     = (const float*)d_in[0];
  const float* W1    = (const float*)d_in[1];
  const float* d1    = (const float*)d_in[2];
  const float* b1    = (const float*)d_in[3];
  const float* W2    = (const float*)d_in[4];
  const float* d2    = (const float*)d_in[5];
  const float* b2    = (const float*)d_in[6];
  const float* gates = (const float*)d_in[7];
  float* out = (float*)d_out;

  char* ws = (char*)d_ws;
  short* wn1s  = (short*)ws;                                  // 5,242,880 B
  short* wn2s  = (short*)(ws + 5242880);                      // 5,242,880 B
  float* expc4 = (float*)(ws + 10485760);                     //   163,840 B
  float* cmaxp = (float*)(ws + 10649600);                     //     1,280 B

  hipLaunchKernelGGL(prep_fused_kernel, dim3(320), dim3(1024), 0, stream,
                     W1, d1, W2, d2, wn1s, wn2s, expc4, cmaxp);
  hipLaunchKernelGGL(bnaf_main_kernel, dim3(256), dim3(1024), 0, stream,
                     x, b1, b2, gates, wn1s, wn2s, expc4, cmaxp, out);
}